// Round 7
// baseline (454.182 us; speedup 1.0000x reference)
//
#include <hip/hip_runtime.h>
#include <math.h>

// StatisticalFeatureLoss — R6: scatter-ring pipeline with CROSS-ITERATION
// bperm pipelining. At iter i: consume windows exchanged at i-1, issue
// exchanges for i+1 (same registers, after last read). DS latency fully
// hidden behind the iteration body. Uniform ring depth D = 3R+2; emit lag
// 2R+1. Zero LDS arrays, zero shift moves, zero exposed DS/VMEM latency.

static constexpr int H = 512, W = 512, PLANES = 48;
static constexpr float EPSF = 1e-8f;

__global__ void init_acc_kernel(double* acc) {
    if (threadIdx.x < 4) acc[threadIdx.x] = 0.0;
}

__global__ void final_kernel(const double* __restrict__ acc, float* __restrict__ out) {
    if (threadIdx.x == 0) {
        const double npix = (double)PLANES * H * W;
        double tot = acc[0] + acc[1] + 0.5 * acc[2] + 0.001 * acc[3];
        out[0] = (float)(tot / (npix * 12.0));
    }
}

__device__ __forceinline__ float bperm(int addr, float v) {
    return __int_as_float(__builtin_amdgcn_ds_bpermute(addr, __float_as_int(v)));
}

template <int K, int BAND, int D, int NSTRIP>
__global__ __launch_bounds__(256)
void stat_kernel(const float* __restrict__ pred, const float* __restrict__ targ,
                 double* __restrict__ acc) {
    constexpr int R  = K / 2;
    constexpr int OW = 64 - 4 * R;            // valid output cols per strip
    constexpr int NBAND = H / BAND;
    constexpr int T  = BAND + 4 * R + 1;      // iterations (emit z = y-2R-1)
    constexpr int Tp = ((T + D - 1) / D) * D;
    static_assert(D >= 3 * R + 2, "ring depth");

    const int wv    = threadIdx.x >> 6;
    const int wid   = blockIdx.x * 4 + wv;
    const int band  = wid % NBAND;
    const int tmp   = wid / NBAND;
    const int strip = tmp % NSTRIP;
    const int plane = tmp / NSTRIP;
    const int t     = threadIdx.x & 63;
    const int gc0   = strip * OW - 2 * R + t;
    const int y0    = band * BAND - 2 * R;

    const bool  iva     = (unsigned)gc0 < (unsigned)W;
    const float colmask = iva ? 1.f : 0.f;
    const float emask   = (t >= 2 * R && t < 2 * R + OW && gc0 < W) ? 1.f : 0.f;

    int adr[K];
#pragma unroll
    for (int j = 0; j < K; ++j) adr[j] = (t - R + j) << 2;

    // Gaussian weights (reference numerics), lane-uniform in SGPRs
    float g[K];
    {
        const float sigma = (float)K / 6.0f;
        const float inv2s2 = 1.0f / (2.0f * sigma * sigma);
        float s = 0.0f;
#pragma unroll
        for (int i = 0; i < K; ++i) {
            float c = (float)(i - K / 2);
            g[i] = expf(-c * c * inv2s2);
            s += g[i];
        }
#pragma unroll
        for (int i = 0; i < K; ++i)
            g[i] = __int_as_float(__builtin_amdgcn_readfirstlane(__float_as_int(g[i] / s)));
    }

    const float* src0 = pred + (size_t)plane * H * W + gc0;
    const float* src1 = targ + (size_t)plane * H * W + gc0;

    auto loadrow = [&](int s, int y) -> float {
        float v = 0.f;
        if (iva && (unsigned)y < (unsigned)H)
            v = (s == 0 ? src0 : src1)[(long)y << 9];
        return v;
    };

    // Rings (slot = (row - y0) mod D; zero-init so early stale reads are
    // finite; all garbage lands in never-emitted rows / overwritten slots)
    float mn[2][D] = {}, msq[2][D] = {}, m3a[2][D] = {}, m4a[2][D] = {}, xr[2][D] = {};
    float w[2][K];            // windows of x[y] (exchanged last iter)
    float wc[2][K] = {};      // windows of xcm[y-R-1] (exchanged last iter)
    float pf[2];              // next row to exchange (y+1)
    float featp[4];
    float sums[4] = {0.f, 0.f, 0.f, 0.f};

    // Prologue: exchange x[y0] into w; prefetch row y0+1
#pragma unroll
    for (int s = 0; s < 2; ++s) {
        const float x0 = loadrow(s, y0);
#pragma unroll
        for (int j = 0; j < K; ++j) w[s][j] = (j == R) ? x0 : bperm(adr[j], x0);
        pf[s] = loadrow(s, y0 + 1);
    }

    for (int yy = 0; yy < Tp; yy += D) {
#pragma unroll
        for (int u = 0; u < D; ++u) {
            const int i = yy + u;          // i % D == u (D | yy)
            const int y = y0 + i;
            const float rmask = (((unsigned)(y - R) < (unsigned)H) ? 1.f : 0.f) * colmask;
            const bool emit = (i >= 4 * R + 1) && (i < T);
#pragma unroll
            for (int s = 0; s < 2; ++s) {
                // --- consume w = windows of x[y] ---
                const float x = w[s][R];
                float hx = 0.f, hq = 0.f;
#pragma unroll
                for (int j = 0; j < K; ++j) {
                    hx += g[j] * w[s][j];
                    hq += g[j] * (w[s][j] * w[s][j]);
                }
                // --- issue next-row exchange into w (consume at i+1) ---
                const float xnext = pf[s];
                pf[s] = loadrow(s, y + 2);
#pragma unroll
                for (int j = 0; j < K; ++j)
                    w[s][j] = (j == R) ? xnext : bperm(adr[j], xnext);

                // --- scatter mn/msq (rows y±R); d==K-1 overwrites (first) ---
#pragma unroll
                for (int d = 0; d < K; ++d) {
                    const int sl = (u + d - R + 3 * D) % D;
                    if (d == K - 1) { mn[s][sl] = g[d] * hx; msq[s][sl] = g[d] * hq; }
                    else           { mn[s][sl] += g[d] * hx; msq[s][sl] += g[d] * hq; }
                }
                xr[s][u] = x;

                // --- xcm for row y-R (mean just completed via d==0 term) ---
                const float xold  = xr[s][(u - R + 3 * D) % D];
                const float mean1 = mn[s][(u - R + 3 * D) % D];
                const float xcm   = (xold - mean1) * rmask;

                // --- consume wc = windows of xcm[y-R-1] ---
                float v3 = 0.f, v4 = 0.f;
#pragma unroll
                for (int j = 0; j < K; ++j) {
                    const float c2 = wc[s][j] * wc[s][j];
                    v3 += g[j] * (c2 * wc[s][j]);
                    v4 += g[j] * (c2 * c2);
                }
                // --- issue xcm exchange into wc (consume at i+1) ---
#pragma unroll
                for (int j = 0; j < K; ++j)
                    wc[s][j] = (j == R) ? xcm : bperm(adr[j], xcm);

                // --- scatter m3a/m4a (v3 row q = y-R-1 -> rows q±R) ---
#pragma unroll
                for (int d = 0; d < K; ++d) {
                    const int sl = (u + d - 2 * R - 1 + 3 * D) % D;
                    if (d == K - 1) { m3a[s][sl] = g[d] * v3; m4a[s][sl] = g[d] * v4; }
                    else           { m3a[s][sl] += g[d] * v3; m4a[s][sl] += g[d] * v4; }
                }

                // --- emit output row z = y-2R-1 (completed this iter) ---
                if (emit) {
                    const int se = (u - 2 * R - 1 + 3 * D) % D;
                    const float mean = mn[s][se];
                    const float var  = fmaxf(msq[s][se] - mean * mean, EPSF);
                    const float sd   = sqrtf(var);
                    const float skew = __fdividef(m3a[s][se], sd * var + EPSF);
                    const float kurt = __fdividef(m4a[s][se], var * var + EPSF);
                    if (s == 0) {
                        featp[0] = mean; featp[1] = var; featp[2] = skew; featp[3] = kurt;
                    } else {
                        sums[0] += fabsf(featp[0] - mean);
                        sums[1] += fabsf(featp[1] - var);
                        sums[2] += fabsf(featp[2] - skew);
                        sums[3] += fabsf(featp[3] - kurt);
                    }
                }
            }
        }
    }

    // per-wave reduction, one cross-wave LDS pass, 4 atomics per block
    __shared__ float red[4][4];
#pragma unroll
    for (int f = 0; f < 4; ++f) {
        float v = sums[f] * emask;
#pragma unroll
        for (int off = 32; off > 0; off >>= 1) v += __shfl_down(v, off, 64);
        if (t == 0) red[wv][f] = v;
    }
    __syncthreads();
    if (threadIdx.x < 4) {
        float v = red[0][threadIdx.x] + red[1][threadIdx.x]
                + red[2][threadIdx.x] + red[3][threadIdx.x];
        atomicAdd(&acc[threadIdx.x], (double)v);
    }
}

extern "C" void kernel_launch(void* const* d_in, const int* in_sizes, int n_in,
                              void* d_out, int out_size, void* d_ws, size_t ws_size,
                              hipStream_t stream) {
    const float* pred = (const float*)d_in[0];
    const float* targ = (const float*)d_in[1];
    double* acc = (double*)d_ws;
    float* out = (float*)d_out;

    init_acc_kernel<<<1, 64, 0, stream>>>(acc);

    // K, BAND, D(>=3R+2), NSTRIP; 4 independent waves per block
    stat_kernel<3,  64,  5,  9><<<dim3(48 *  9 * 8 / 4), 256, 0, stream>>>(pred, targ, acc);
    stat_kernel<5,  64,  8, 10><<<dim3(48 * 10 * 8 / 4), 256, 0, stream>>>(pred, targ, acc);
    stat_kernel<7, 128, 11, 10><<<dim3(48 * 10 * 4 / 4), 256, 0, stream>>>(pred, targ, acc);

    final_kernel<<<1, 64, 0, stream>>>(acc, out);
}